// Round 6
// baseline (643.211 us; speedup 1.0000x reference)
//
#include <hip/hip_runtime.h>
#include <stdint.h>

// Axial attention (H axis), N=8 H=128 W=128 C=512, GROUPS=8, gp=64.
// Pipeline: wconv -> xconv(bf16+permute) -> QKV GEMM -> attn -> outproj.
// GEMM: 256x128 block, 8 waves (4x2), BK=32, 3-slab LDS rotation (72KB -> 2 blocks/CU),
// one barrier + counted vmcnt(3) per K-step (T3/T4), setprio (T5), slot-XOR swizzle (T2).
// ws: Q/K/V as separate [M][512] planes (dense 1KB rows); O overwrites xb ([M][512]).

typedef __attribute__((ext_vector_type(4))) float f32x4;
typedef __attribute__((ext_vector_type(8))) short bf16x8;
typedef unsigned short u16;
typedef unsigned int u32;

#define CBAR() asm volatile("" ::: "memory")
#define SBAR() do { CBAR(); __builtin_amdgcn_s_barrier(); CBAR(); } while(0)
#define LGKM0() do { asm volatile("s_waitcnt lgkmcnt(0)" ::: "memory"); __builtin_amdgcn_sched_barrier(0); } while(0)
#define VMC(n) asm volatile("s_waitcnt vmcnt(" #n ")" ::: "memory")

static __device__ __forceinline__ u16 f2bf(float f){
    union { float f; u32 u; } v; v.f = f;
    u32 r = v.u + 0x7fffu + ((v.u >> 16) & 1u);   // RNE
    return (u16)(r >> 16);
}

static __device__ __forceinline__ void gload16(const void* g, void* l){
    __builtin_amdgcn_global_load_lds((const __attribute__((address_space(1))) void*)g,
                                     (__attribute__((address_space(3))) void*)l, 16, 0, 0);
}

// ---------------- weights fp32 -> bf16 ----------------
__global__ void k_wconv(const float* __restrict__ Wq, const float* __restrict__ Wk,
                        const float* __restrict__ Wv, const float* __restrict__ Wo,
                        u16* __restrict__ Wcat, u16* __restrict__ Wob){
    int e = (blockIdx.x * 256 + threadIdx.x) * 4;
    if (e < 1536*512) {
        int row = e >> 9, col = e & 511;
        const float* s = (row < 512) ? (Wq + row*512)
                        : (row < 1024 ? Wk + (row-512)*512 : Wv + (row-1024)*512);
        float4 v = *(const float4*)(s + col);
        ushort4 o = { f2bf(v.x), f2bf(v.y), f2bf(v.z), f2bf(v.w) };
        *(ushort4*)(Wcat + e) = o;
    } else {
        int e2 = e - 1536*512;
        float4 v = *(const float4*)(Wo + e2);
        ushort4 o = { f2bf(v.x), f2bf(v.y), f2bf(v.z), f2bf(v.w) };
        *(ushort4*)(Wob + e2) = o;
    }
}

// ---------------- x fp32 (N,H,W,C) -> xb bf16 [(n0+nl)*128+h][512] ----------------
__global__ void k_xconv(const float* __restrict__ x, u16* __restrict__ xb, int n0){
    int t = blockIdx.x * 256 + threadIdx.x;
    int ml = t >> 6;                 // chunk-local token row
    int c0 = (t & 63) << 3;          // 8 channels per thread
    int nl = ml >> 7, h = ml & 127;
    int n = n0 + nl, nb = n >> 7, w = n & 127;
    const float* src = x + (size_t)((nb*128 + h)*128 + w) * 512 + c0;
    float4 a = *(const float4*)(src);
    float4 b = *(const float4*)(src + 4);
    uint4 o;
    o.x = (u32)f2bf(a.x) | ((u32)f2bf(a.y) << 16);
    o.y = (u32)f2bf(a.z) | ((u32)f2bf(a.w) << 16);
    o.z = (u32)f2bf(b.x) | ((u32)f2bf(b.y) << 16);
    o.w = (u32)f2bf(b.z) | ((u32)f2bf(b.w) << 16);
    *(uint4*)(xb + (size_t)ml*512 + c0) = o;
}

// ---------------- 256x128 GEMM, 3-slab pipeline: C[MxN] = A[MxK=512] * B^T ----------------
// slab s (24KB): A [256 rows][64B] at +0, B [128 rows][64B] at +16384.
// Slot-XOR (T2): LDS slot q of row r holds global kk-chunk (q ^ ((r>>1)&3)); read at
// slot lg^((r>>1)&3). A b128 sweep of 8 lanes then covers all 32 banks exactly once
// (round-3 PMC: 0 conflicts; round-5 unswizzled: 2.5e7).
// Step t: stage slab (t+2)%3; read frags from slab t%3; lgkm0; 16 MFMA; vmcnt(3); barrier.
template<int NCOL, bool OUTPROJ>
__global__ __launch_bounds__(512, 4) void k_gemm3(const u16* __restrict__ A, const u16* __restrict__ B,
                                                  void* __restrict__ Cout, const float* __restrict__ bias,
                                                  int n0, int nrow, int planesz){
    extern __shared__ char smc[];
    const int tid = threadIdx.x;
    const int wid = tid >> 6, lane = tid & 63, lg = lane >> 4, li = lane & 15;
    const int wr = wid >> 1, wc = wid & 1;           // 4 x 2 wave grid, wave out 64x64
    const int bid = blockIdx.x;
    const int xcd = bid & 7, l = bid >> 3;
    const int row_tile = xcd * (nrow >> 3) + l / NCOL;
    const int col_tile = l % NCOL;
    const int m0 = row_tile * 256, nn0 = col_tile * 128;

    // stage slab s, K-window [kb, kb+32): A 2KB/wave (2 chunks), B 1KB/wave.
    // dest linear (lane*16); source pre-swizzled so LDS slot q holds chunk q^((r>>1)&3).
    auto stage = [&](int s, int kb){
        char* sl = smc + s*24576;
        #pragma unroll
        for (int i = 0; i < 2; ++i) {
            int R = wid*32 + i*16;
            int r = R + (lane >> 2);
            int cq = (lane & 3) ^ ((r >> 1) & 3);
            gload16((const char*)(A + (size_t)(m0 + r)*512 + kb) + cq*16, sl + R*64);
        }
        int rb = wid*16 + (lane >> 2);
        int cqb = (lane & 3) ^ ((rb >> 1) & 3);
        gload16((const char*)(B + (size_t)(nn0 + rb)*512 + kb) + cqb*16, sl + 16384 + wid*1024);
    };

    f32x4 acc[4][4];
    #pragma unroll
    for (int i = 0; i < 4; ++i)
        #pragma unroll
        for (int j = 0; j < 4; ++j)
            acc[i][j] = f32x4{0.f, 0.f, 0.f, 0.f};

    // prologue: slabs 0,1 for steps 0,1; wait slab0 complete
    stage(0, 0);
    stage(1, 32);
    VMC(3);
    SBAR();

    for (int t = 0; t < 16; ++t) {
        const int sc = t % 3;
        char* sl = smc + sc*24576;

        if (t < 14) stage((sc + 2) % 3, (t + 2) * 32);

        bf16x8 af[4], bfr[4];
        #pragma unroll
        for (int f = 0; f < 4; ++f) {
            int ra = wr*64 + f*16 + li;
            af[f] = *(const bf16x8*)(sl + ra*64 + (((lg ^ (ra >> 1)) & 3) << 4));
        }
        #pragma unroll
        for (int f = 0; f < 4; ++f) {
            int rb = wc*64 + f*16 + li;
            bfr[f] = *(const bf16x8*)(sl + 16384 + rb*64 + (((lg ^ (rb >> 1)) & 3) << 4));
        }

        LGKM0();
        __builtin_amdgcn_s_setprio(1);
        #pragma unroll
        for (int fi = 0; fi < 4; ++fi)
            #pragma unroll
            for (int fj = 0; fj < 4; ++fj)
                acc[fi][fj] = __builtin_amdgcn_mfma_f32_16x16x32_bf16(af[fi], bfr[fj], acc[fi][fj], 0, 0, 0);
        __builtin_amdgcn_s_setprio(0);

        if (t < 13) { VMC(3); } else { VMC(0); }
        SBAR();
    }

    // epilogue
    if (!OUTPROJ) {
        // C = Q/K/V planes, each [chunkrows][512]; plane from output col range
        u16* Cp = (u16*)Cout + (size_t)(nn0 >> 9) * planesz;
        const int cb = (nn0 & 511) + wc*64;
        #pragma unroll
        for (int fi = 0; fi < 4; ++fi)
            #pragma unroll
            for (int fj = 0; fj < 4; ++fj)
                #pragma unroll
                for (int r = 0; r < 4; ++r) {
                    int row = m0 + wr*64 + fi*16 + lg*4 + r;
                    int col = cb + fj*16 + li;
                    Cp[(size_t)row*512 + col] = f2bf(acc[fi][fj][r]);
                }
    } else {
        float* C = (float*)Cout;
        #pragma unroll
        for (int fi = 0; fi < 4; ++fi)
            #pragma unroll
            for (int fj = 0; fj < 4; ++fj)
                #pragma unroll
                for (int r = 0; r < 4; ++r) {
                    int row = m0 + wr*64 + fi*16 + lg*4 + r;   // chunk-local token
                    int col = nn0 + wc*64 + fj*16 + li;
                    int mg = n0*128 + row;
                    int n = mg >> 7, ii = mg & 127;            // n = nb*128+w, ii = h
                    int nb = n >> 7, w = n & 127;
                    C[(size_t)((nb*128 + ii)*128 + w) * 512 + col] = acc[fi][fj][r] + bias[col];
                }
    }
}

// ---------------- attention: one block per (n_local, group), 4 waves x 32 rows ----------------
__global__ __launch_bounds__(256, 2) void k_attn(const u16* __restrict__ Qpl, const u16* __restrict__ Kpl,
                                                 const u16* __restrict__ Vpl, u16* __restrict__ Ob){
    // LDS: [0,16K) Qs swz, [16K,32K) Ks swz; P overlays [0,34816) after S-phase;
    //      Vt [34816, 34816+17408): [c=64][stride 272B] bf16
    __shared__ char sm[52224];
    const int g = blockIdx.x;
    const int nl = blockIdx.y;
    const int tid = threadIdx.x;
    const int wid = tid >> 6, lane = tid & 63, lg = lane >> 4, li = lane & 15;

    const u16* Qg = Qpl + (size_t)nl*128*512 + g*64;
    const u16* Kg = Kpl + (size_t)nl*128*512 + g*64;
    const u16* Vg = Vpl + (size_t)nl*128*512 + g*64;
    u16*       Og = Ob  + (size_t)nl*128*512 + g*64;

    #pragma unroll
    for (int it = 0; it < 4; ++it) {
        int gi = it*256 + tid;
        int row = gi >> 3, gs = gi & 7;
        int sw = (gs ^ (row & 7)) << 4;
        gload16((const char*)(Qg + (size_t)row*512) + sw, sm + it*4096 + wid*1024);
        gload16((const char*)(Kg + (size_t)row*512) + sw, sm + 16384 + it*4096 + wid*1024);
    }
    {   // V transposed: Vt[c][j] — vectorized global loads, scalar LDS scatter
        int j = tid & 127, ch = tid >> 7;
        const u16* src = Vg + (size_t)j*512 + ch*32;
        uint4 a0 = *(const uint4*)(src);
        uint4 a1 = *(const uint4*)(src + 8);
        uint4 a2 = *(const uint4*)(src + 16);
        uint4 a3 = *(const uint4*)(src + 24);
        u32 w[16] = {a0.x,a0.y,a0.z,a0.w, a1.x,a1.y,a1.z,a1.w,
                     a2.x,a2.y,a2.z,a2.w, a3.x,a3.y,a3.z,a3.w};
        char* dst = sm + 34816 + ch*32*272 + j*2;
        #pragma unroll
        for (int cc = 0; cc < 32; ++cc) {
            u32 word = w[cc >> 1];
            u16 val = (cc & 1) ? (u16)(word >> 16) : (u16)(word & 0xffffu);
            *(u16*)(dst + cc*272) = val;
        }
    }
    __syncthreads();

    const int i0w = wid*32;
    f32x4 s[2][8];
    #pragma unroll
    for (int t = 0; t < 2; ++t)
        #pragma unroll
        for (int tj = 0; tj < 8; ++tj)
            s[t][tj] = f32x4{0.f,0.f,0.f,0.f};

    #pragma unroll
    for (int ks = 0; ks < 2; ++ks) {
        bf16x8 qf[2];
        #pragma unroll
        for (int t = 0; t < 2; ++t) {
            int ra = i0w + t*16 + li;
            qf[t] = *(const bf16x8*)(sm + ra*128 + ((ks*64 + lg*16) ^ ((ra & 7) << 4)));
        }
        #pragma unroll
        for (int tj = 0; tj < 8; ++tj) {
            int rb = tj*16 + li;
            bf16x8 kf = *(const bf16x8*)(sm + 16384 + rb*128 + ((ks*64 + lg*16) ^ ((rb & 7) << 4)));
            #pragma unroll
            for (int t = 0; t < 2; ++t)
                s[t][tj] = __builtin_amdgcn_mfma_f32_16x16x32_bf16(qf[t], kf, s[t][tj], 0, 0, 0);
        }
    }
    __syncthreads();   // Q/K LDS dead -> P overlay is now safe

    // wave-parallel softmax over j (scale 1/8 folded into exp arg)
    char* pb = sm + wid*8704;     // per-wave P [32 rows][272B stride]
    #pragma unroll
    for (int t = 0; t < 2; ++t) {
        #pragma unroll
        for (int r = 0; r < 4; ++r) {
            float mx = -1e30f;
            #pragma unroll
            for (int tj = 0; tj < 8; ++tj) mx = fmaxf(mx, s[t][tj][r]);
            #pragma unroll
            for (int off = 1; off < 16; off <<= 1) mx = fmaxf(mx, __shfl_xor(mx, off, 64));
            float p[8]; float sum = 0.f;
            #pragma unroll
            for (int tj = 0; tj < 8; ++tj) { p[tj] = __expf((s[t][tj][r] - mx)*0.125f); sum += p[tj]; }
            #pragma unroll
            for (int off = 1; off < 16; off <<= 1) sum += __shfl_xor(sum, off, 64);
            float inv = 1.0f / sum;
            int prow = t*16 + lg*4 + r;
            #pragma unroll
            for (int tj = 0; tj < 8; ++tj)
                *(u16*)(pb + prow*272 + (tj*16 + li)*2) = f2bf(p[tj]*inv);
        }
    }

    // O = P @ V
    f32x4 o[2][4];
    #pragma unroll
    for (int t = 0; t < 2; ++t)
        #pragma unroll
        for (int tc = 0; tc < 4; ++tc)
            o[t][tc] = f32x4{0.f,0.f,0.f,0.f};

    #pragma unroll
    for (int ks = 0; ks < 4; ++ks) {
        bf16x8 pf[2];
        #pragma unroll
        for (int t = 0; t < 2; ++t)
            pf[t] = *(const bf16x8*)(pb + (t*16 + li)*272 + (ks*64 + lg*16));
        #pragma unroll
        for (int tc = 0; tc < 4; ++tc) {
            bf16x8 vf = *(const bf16x8*)(sm + 34816 + (tc*16 + li)*272 + (ks*64 + lg*16));
            #pragma unroll
            for (int t = 0; t < 2; ++t)
                o[t][tc] = __builtin_amdgcn_mfma_f32_16x16x32_bf16(pf[t], vf, o[t][tc], 0, 0, 0);
        }
    }

    #pragma unroll
    for (int t = 0; t < 2; ++t)
        #pragma unroll
        for (int tc = 0; tc < 4; ++tc)
            #pragma unroll
            for (int r = 0; r < 4; ++r) {
                int irow = i0w + t*16 + lg*4 + r;
                int col = tc*16 + li;
                Og[(size_t)irow*512 + col] = f2bf(o[t][tc][r]);
            }
}

extern "C" void kernel_launch(void* const* d_in, const int* in_sizes, int n_in,
                              void* d_out, int out_size, void* d_ws, size_t ws_size,
                              hipStream_t stream){
    const float* x  = (const float*)d_in[0];
    const float* Wq = (const float*)d_in[1];
    const float* Wk = (const float*)d_in[2];
    const float* Wv = (const float*)d_in[3];
    const float* Wo = (const float*)d_in[4];
    const float* bo = (const float*)d_in[5];

    char* ws = (char*)d_ws;
    u16* Wcat = (u16*)ws;               // 1536*512 bf16
    u16* Wob  = Wcat + 1536*512;        // 512*512 bf16 ; weights end at 2097152 B

    // chunk over the 1024 attention rows: per chunk = CN*128*512*2 (xb) + 3x same (QKV planes)
    int CN = 1024;
    while (CN > 64 && (size_t)2097152 + (size_t)CN*524288 > ws_size) CN >>= 1;
    u16* xb   = (u16*)(ws + 2097152);      // also reused as O buffer by attn/outproj
    u16* QKV2 = xb + (size_t)CN*128*512;   // 3 planes [CN*128][512]
    int planesz = CN*128*512;

    // 72 KiB dynamic LDS for the 3-slab GEMMs (idempotent; not a stream op, capture-safe)
    hipFuncSetAttribute((const void*)&k_gemm3<12, false>,
                        hipFuncAttributeMaxDynamicSharedMemorySize, 73728);
    hipFuncSetAttribute((const void*)&k_gemm3<4, true>,
                        hipFuncAttributeMaxDynamicSharedMemorySize, 73728);

    k_wconv<<<1024, 256, 0, stream>>>(Wq, Wk, Wv, Wo, Wcat, Wob);
    int nch = 1024 / CN;
    for (int ch = 0; ch < nch; ++ch) {
        int n0 = ch * CN;
        int nrow = (CN * 128) / 256;    // 256-row tiles in this chunk (divisible by 8 for CN>=16)
        k_xconv<<<CN*32, 256, 0, stream>>>(x, xb, n0);
        k_gemm3<12, false><<<nrow*12, 512, 73728, stream>>>(xb, Wcat, QKV2, nullptr, 0, nrow, planesz);
        k_attn<<<dim3(8, CN), 256, 0, stream>>>(QKV2, QKV2 + planesz, QKV2 + 2*(size_t)planesz, xb);
        k_gemm3<4, true ><<<nrow*4,  512, 73728, stream>>>(xb, Wob, d_out, bo, n0, nrow, 0);
    }
}

// Round 7
// 632.200 us; speedup vs baseline: 1.0174x; 1.0174x over previous
//
#include <hip/hip_runtime.h>
#include <stdint.h>

// Axial attention (H axis), N=8 H=128 W=128 C=512, GROUPS=8, gp=64.
// Pipeline: wconv -> xconv(bf16+permute) -> QKV GEMM -> attn -> outproj.
// GEMM (k_gemm4): 256x256 block, 8 waves (2x4, wave-out 128x64), BK=32 K-steps,
// 4 rotating 32KB K-step buffers (128 KiB LDS), depth-3 prefetch (stage t+3),
// ONE counted vmcnt(8) per step, slot-XOR swizzle (R6-verified, conflicts=0).
// ws: Q/K/V as separate [M][512] planes; O overwrites xb ([M][512]).

typedef __attribute__((ext_vector_type(4))) float f32x4;
typedef __attribute__((ext_vector_type(8))) short bf16x8;
typedef unsigned short u16;
typedef unsigned int u32;

#define CBAR() asm volatile("" ::: "memory")
#define SBAR() do { CBAR(); __builtin_amdgcn_s_barrier(); CBAR(); } while(0)
#define LGKM0() do { asm volatile("s_waitcnt lgkmcnt(0)" ::: "memory"); __builtin_amdgcn_sched_barrier(0); } while(0)
#define VMC(n) asm volatile("s_waitcnt vmcnt(" #n ")" ::: "memory")

static __device__ __forceinline__ u16 f2bf(float f){
    union { float f; u32 u; } v; v.f = f;
    u32 r = v.u + 0x7fffu + ((v.u >> 16) & 1u);   // RNE
    return (u16)(r >> 16);
}

static __device__ __forceinline__ void gload16(const void* g, void* l){
    __builtin_amdgcn_global_load_lds((const __attribute__((address_space(1))) void*)g,
                                     (__attribute__((address_space(3))) void*)l, 16, 0, 0);
}

// ---------------- weights fp32 -> bf16 ----------------
__global__ void k_wconv(const float* __restrict__ Wq, const float* __restrict__ Wk,
                        const float* __restrict__ Wv, const float* __restrict__ Wo,
                        u16* __restrict__ Wcat, u16* __restrict__ Wob){
    int e = (blockIdx.x * 256 + threadIdx.x) * 4;
    if (e < 1536*512) {
        int row = e >> 9, col = e & 511;
        const float* s = (row < 512) ? (Wq + row*512)
                        : (row < 1024 ? Wk + (row-512)*512 : Wv + (row-1024)*512);
        float4 v = *(const float4*)(s + col);
        ushort4 o = { f2bf(v.x), f2bf(v.y), f2bf(v.z), f2bf(v.w) };
        *(ushort4*)(Wcat + e) = o;
    } else {
        int e2 = e - 1536*512;
        float4 v = *(const float4*)(Wo + e2);
        ushort4 o = { f2bf(v.x), f2bf(v.y), f2bf(v.z), f2bf(v.w) };
        *(ushort4*)(Wob + e2) = o;
    }
}

// ---------------- x fp32 (N,H,W,C) -> xb bf16 [(n0+nl)*128+h][512] ----------------
__global__ void k_xconv(const float* __restrict__ x, u16* __restrict__ xb, int n0){
    int t = blockIdx.x * 256 + threadIdx.x;
    int ml = t >> 6;                 // chunk-local token row
    int c0 = (t & 63) << 3;          // 8 channels per thread
    int nl = ml >> 7, h = ml & 127;
    int n = n0 + nl, nb = n >> 7, w = n & 127;
    const float* src = x + (size_t)((nb*128 + h)*128 + w) * 512 + c0;
    float4 a = *(const float4*)(src);
    float4 b = *(const float4*)(src + 4);
    uint4 o;
    o.x = (u32)f2bf(a.x) | ((u32)f2bf(a.y) << 16);
    o.y = (u32)f2bf(a.z) | ((u32)f2bf(a.w) << 16);
    o.z = (u32)f2bf(b.x) | ((u32)f2bf(b.y) << 16);
    o.w = (u32)f2bf(b.z) | ((u32)f2bf(b.w) << 16);
    *(uint4*)(xb + (size_t)ml*512 + c0) = o;
}

// ---------------- 256x256 GEMM, 4-buffer depth-3 pipeline: C = A[Mx512] * B^T ----------------
// Buf b (32KB) = A slab [256 rows][64B] + B slab [256 rows][64B] (one BK=32 K-window).
// Swizzle (R6-verified, 0 conflicts): LDS 16B-slot q of row r holds global chunk q^((r>>1)&3);
// frag read at slot lg^((r>>1)&3).
// Step t (2 phases): p0 {read 4 A-frags + 4 B-frags (buf t&3); stageA(t+3); barrier; lgkm0;
// 16 MFMA acc[0..3][*]; barrier}  p1 {read 4 A-frags; stageB(t+3); barrier; lgkm0; 16 MFMA
// acc[4..7][*]; vmcnt(8) [retires step t+1's 4 loads; tail 4->0]; barrier}.
// Hazard: stage(t+3) targets buf (t-1)&3, read-complete at step t-1's lgkm -> issue-after-use.
template<int NCOL, bool OUTPROJ>
__global__ __launch_bounds__(512, 2) void k_gemm4(const u16* __restrict__ A, const u16* __restrict__ B,
                                                  void* __restrict__ Cout, const float* __restrict__ bias,
                                                  int n0, int nrow, int planesz){
    extern __shared__ char smc[];
    const int tid = threadIdx.x;
    const int wid = tid >> 6, lane = tid & 63, lg = lane >> 4, li = lane & 15;
    const int wm = wid >> 2, wn = wid & 3;           // 2 x 4 wave grid, wave out 128x64
    const int bid = blockIdx.x;
    const int xcd = bid & 7, l = bid >> 3;
    const int row_tile = xcd * (nrow >> 3) + l / NCOL;
    const int col_tile = l % NCOL;
    const int m0 = row_tile * 256, nn0 = col_tile * 256;

    // stage A/B slab of K-step st into buf st&3 (2 gload16/wave each; 32 rows/wave)
    auto stageA = [&](int st){
        char* sl = smc + (st & 3)*32768;
        const int kb = st*32;
        #pragma unroll
        for (int i = 0; i < 2; ++i) {
            int R = wid*32 + i*16;
            int r = R + (lane >> 2);
            int cq = (lane & 3) ^ ((r >> 1) & 3);
            gload16((const char*)(A + (size_t)(m0 + r)*512 + kb) + cq*16, sl + R*64);
        }
    };
    auto stageB = [&](int st){
        char* sl = smc + (st & 3)*32768 + 16384;
        const int kb = st*32;
        #pragma unroll
        for (int i = 0; i < 2; ++i) {
            int R = wid*32 + i*16;
            int r = R + (lane >> 2);
            int cq = (lane & 3) ^ ((r >> 1) & 3);
            gload16((const char*)(B + (size_t)(nn0 + r)*512 + kb) + cq*16, sl + R*64);
        }
    };

    f32x4 acc[8][4];
    #pragma unroll
    for (int i = 0; i < 8; ++i)
        #pragma unroll
        for (int j = 0; j < 4; ++j)
            acc[i][j] = f32x4{0.f, 0.f, 0.f, 0.f};

    // prologue: stage steps 0,1,2 (12 loads/wave); wait step 0 landed (8 = steps 1,2 in flight)
    stageA(0); stageB(0);
    stageA(1); stageB(1);
    stageA(2); stageB(2);
    VMC(8);
    SBAR();

    bf16x8 af[4], bfr[4];
    for (int t = 0; t < 16; ++t) {
        char* sl = smc + (t & 3)*32768;

        // ---- p0: frags A[0..3] + B[0..3], MFMA upper half
        #pragma unroll
        for (int f = 0; f < 4; ++f) {
            int ra = wm*128 + f*16 + li;
            af[f] = *(const bf16x8*)(sl + ra*64 + (((lg ^ (ra >> 1)) & 3) << 4));
        }
        #pragma unroll
        for (int f = 0; f < 4; ++f) {
            int rb = wn*64 + f*16 + li;
            bfr[f] = *(const bf16x8*)(sl + 16384 + rb*64 + (((lg ^ (rb >> 1)) & 3) << 4));
        }
        if (t < 13) stageA(t + 3);
        SBAR(); LGKM0();
        __builtin_amdgcn_s_setprio(1);
        #pragma unroll
        for (int fi = 0; fi < 4; ++fi)
            #pragma unroll
            for (int fj = 0; fj < 4; ++fj)
                acc[fi][fj] = __builtin_amdgcn_mfma_f32_16x16x32_bf16(af[fi], bfr[fj], acc[fi][fj], 0, 0, 0);
        __builtin_amdgcn_s_setprio(0);
        SBAR();

        // ---- p1: frags A[4..7] (B in regs), MFMA lower half
        #pragma unroll
        for (int f = 0; f < 4; ++f) {
            int ra = wm*128 + (4 + f)*16 + li;
            af[f] = *(const bf16x8*)(sl + ra*64 + (((lg ^ (ra >> 1)) & 3) << 4));
        }
        if (t < 13) stageB(t + 3);
        SBAR(); LGKM0();
        __builtin_amdgcn_s_setprio(1);
        #pragma unroll
        for (int fi = 0; fi < 4; ++fi)
            #pragma unroll
            for (int fj = 0; fj < 4; ++fj)
                acc[4 + fi][fj] = __builtin_amdgcn_mfma_f32_16x16x32_bf16(af[fi], bfr[fj], acc[4 + fi][fj], 0, 0, 0);
        __builtin_amdgcn_s_setprio(0);
        if (t < 13)      { VMC(8); }   // retire step t+1's 4 loads; 8 in flight (t+2,t+3)
        else if (t == 13){ VMC(4); }   // retire step 14
        else if (t == 14){ VMC(0); }   // retire step 15
        SBAR();
    }

    // epilogue
    if (!OUTPROJ) {
        // C = Q/K/V planes, each [chunkrows][512]; plane from output col range
        u16* Cp = (u16*)Cout + (size_t)(nn0 >> 9) * planesz;
        const int cb = (nn0 & 511) + wn*64;
        #pragma unroll
        for (int mf = 0; mf < 8; ++mf)
            #pragma unroll
            for (int nf = 0; nf < 4; ++nf)
                #pragma unroll
                for (int r = 0; r < 4; ++r) {
                    int row = m0 + wm*128 + mf*16 + lg*4 + r;
                    int col = cb + nf*16 + li;
                    Cp[(size_t)row*512 + col] = f2bf(acc[mf][nf][r]);
                }
    } else {
        float* C = (float*)Cout;
        #pragma unroll
        for (int mf = 0; mf < 8; ++mf)
            #pragma unroll
            for (int nf = 0; nf < 4; ++nf)
                #pragma unroll
                for (int r = 0; r < 4; ++r) {
                    int row = m0 + wm*128 + mf*16 + lg*4 + r;   // chunk-local token
                    int col = nn0 + wn*64 + nf*16 + li;
                    int mg = n0*128 + row;
                    int n = mg >> 7, ii = mg & 127;             // n = nb*128+w, ii = h
                    int nb = n >> 7, w = n & 127;
                    C[(size_t)((nb*128 + ii)*128 + w) * 512 + col] = acc[mf][nf][r] + bias[col];
                }
    }
}

// ---------------- attention: one block per (n_local, group), 4 waves x 32 rows ----------------
__global__ __launch_bounds__(256, 2) void k_attn(const u16* __restrict__ Qpl, const u16* __restrict__ Kpl,
                                                 const u16* __restrict__ Vpl, u16* __restrict__ Ob){
    // LDS: [0,16K) Qs swz, [16K,32K) Ks swz; P overlays [0,34816) after S-phase;
    //      Vt [34816, 34816+17408): [c=64][stride 272B] bf16
    __shared__ char sm[52224];
    const int g = blockIdx.x;
    const int nl = blockIdx.y;
    const int tid = threadIdx.x;
    const int wid = tid >> 6, lane = tid & 63, lg = lane >> 4, li = lane & 15;

    const u16* Qg = Qpl + (size_t)nl*128*512 + g*64;
    const u16* Kg = Kpl + (size_t)nl*128*512 + g*64;
    const u16* Vg = Vpl + (size_t)nl*128*512 + g*64;
    u16*       Og = Ob  + (size_t)nl*128*512 + g*64;

    #pragma unroll
    for (int it = 0; it < 4; ++it) {
        int gi = it*256 + tid;
        int row = gi >> 3, gs = gi & 7;
        int sw = (gs ^ (row & 7)) << 4;
        gload16((const char*)(Qg + (size_t)row*512) + sw, sm + it*4096 + wid*1024);
        gload16((const char*)(Kg + (size_t)row*512) + sw, sm + 16384 + it*4096 + wid*1024);
    }
    {   // V transposed: Vt[c][j] — vectorized global loads, scalar LDS scatter
        int j = tid & 127, ch = tid >> 7;
        const u16* src = Vg + (size_t)j*512 + ch*32;
        uint4 a0 = *(const uint4*)(src);
        uint4 a1 = *(const uint4*)(src + 8);
        uint4 a2 = *(const uint4*)(src + 16);
        uint4 a3 = *(const uint4*)(src + 24);
        u32 w[16] = {a0.x,a0.y,a0.z,a0.w, a1.x,a1.y,a1.z,a1.w,
                     a2.x,a2.y,a2.z,a2.w, a3.x,a3.y,a3.z,a3.w};
        char* dst = sm + 34816 + ch*32*272 + j*2;
        #pragma unroll
        for (int cc = 0; cc < 32; ++cc) {
            u32 word = w[cc >> 1];
            u16 val = (cc & 1) ? (u16)(word >> 16) : (u16)(word & 0xffffu);
            *(u16*)(dst + cc*272) = val;
        }
    }
    __syncthreads();

    const int i0w = wid*32;
    f32x4 s[2][8];
    #pragma unroll
    for (int t = 0; t < 2; ++t)
        #pragma unroll
        for (int tj = 0; tj < 8; ++tj)
            s[t][tj] = f32x4{0.f,0.f,0.f,0.f};

    #pragma unroll
    for (int ks = 0; ks < 2; ++ks) {
        bf16x8 qf[2];
        #pragma unroll
        for (int t = 0; t < 2; ++t) {
            int ra = i0w + t*16 + li;
            qf[t] = *(const bf16x8*)(sm + ra*128 + ((ks*64 + lg*16) ^ ((ra & 7) << 4)));
        }
        #pragma unroll
        for (int tj = 0; tj < 8; ++tj) {
            int rb = tj*16 + li;
            bf16x8 kf = *(const bf16x8*)(sm + 16384 + rb*128 + ((ks*64 + lg*16) ^ ((rb & 7) << 4)));
            #pragma unroll
            for (int t = 0; t < 2; ++t)
                s[t][tj] = __builtin_amdgcn_mfma_f32_16x16x32_bf16(qf[t], kf, s[t][tj], 0, 0, 0);
        }
    }
    __syncthreads();   // Q/K LDS dead -> P overlay is now safe

    // wave-parallel softmax over j (scale 1/8 folded into exp arg)
    char* pb = sm + wid*8704;     // per-wave P [32 rows][272B stride]
    #pragma unroll
    for (int t = 0; t < 2; ++t) {
        #pragma unroll
        for (int r = 0; r < 4; ++r) {
            float mx = -1e30f;
            #pragma unroll
            for (int tj = 0; tj < 8; ++tj) mx = fmaxf(mx, s[t][tj][r]);
            #pragma unroll
            for (int off = 1; off < 16; off <<= 1) mx = fmaxf(mx, __shfl_xor(mx, off, 64));
            float p[8]; float sum = 0.f;
            #pragma unroll
            for (int tj = 0; tj < 8; ++tj) { p[tj] = __expf((s[t][tj][r] - mx)*0.125f); sum += p[tj]; }
            #pragma unroll
            for (int off = 1; off < 16; off <<= 1) sum += __shfl_xor(sum, off, 64);
            float inv = 1.0f / sum;
            int prow = t*16 + lg*4 + r;
            #pragma unroll
            for (int tj = 0; tj < 8; ++tj)
                *(u16*)(pb + prow*272 + (tj*16 + li)*2) = f2bf(p[tj]*inv);
        }
    }

    // O = P @ V
    f32x4 o[2][4];
    #pragma unroll
    for (int t = 0; t < 2; ++t)
        #pragma unroll
        for (int tc = 0; tc < 4; ++tc)
            o[t][tc] = f32x4{0.f,0.f,0.f,0.f};

    #pragma unroll
    for (int ks = 0; ks < 4; ++ks) {
        bf16x8 pf[2];
        #pragma unroll
        for (int t = 0; t < 2; ++t)
            pf[t] = *(const bf16x8*)(pb + (t*16 + li)*272 + (ks*64 + lg*16));
        #pragma unroll
        for (int tc = 0; tc < 4; ++tc) {
            bf16x8 vf = *(const bf16x8*)(sm + 34816 + (tc*16 + li)*272 + (ks*64 + lg*16));
            #pragma unroll
            for (int t = 0; t < 2; ++t)
                o[t][tc] = __builtin_amdgcn_mfma_f32_16x16x32_bf16(pf[t], vf, o[t][tc], 0, 0, 0);
        }
    }

    #pragma unroll
    for (int t = 0; t < 2; ++t)
        #pragma unroll
        for (int tc = 0; tc < 4; ++tc)
            #pragma unroll
            for (int r = 0; r < 4; ++r) {
                int irow = i0w + t*16 + lg*4 + r;
                int col = tc*16 + li;
                Og[(size_t)irow*512 + col] = f2bf(o[t][tc][r]);
            }
}

extern "C" void kernel_launch(void* const* d_in, const int* in_sizes, int n_in,
                              void* d_out, int out_size, void* d_ws, size_t ws_size,
                              hipStream_t stream){
    const float* x  = (const float*)d_in[0];
    const float* Wq = (const float*)d_in[1];
    const float* Wk = (const float*)d_in[2];
    const float* Wv = (const float*)d_in[3];
    const float* Wo = (const float*)d_in[4];
    const float* bo = (const float*)d_in[5];

    char* ws = (char*)d_ws;
    u16* Wcat = (u16*)ws;               // 1536*512 bf16
    u16* Wob  = Wcat + 1536*512;        // 512*512 bf16 ; weights end at 2097152 B

    // chunk over the 1024 attention rows: per chunk = CN*128*512*2 (xb) + 3x same (QKV planes)
    int CN = 1024;
    while (CN > 64 && (size_t)2097152 + (size_t)CN*524288 > ws_size) CN >>= 1;
    u16* xb   = (u16*)(ws + 2097152);      // also reused as O buffer by attn/outproj
    u16* QKV2 = xb + (size_t)CN*128*512;   // 3 planes [CN*128][512]
    int planesz = CN*128*512;

    // 128 KiB dynamic LDS for the 4-buffer GEMMs (idempotent; not a stream op, capture-safe)
    hipFuncSetAttribute((const void*)&k_gemm4<6, false>,
                        hipFuncAttributeMaxDynamicSharedMemorySize, 131072);
    hipFuncSetAttribute((const void*)&k_gemm4<2, true>,
                        hipFuncAttributeMaxDynamicSharedMemorySize, 131072);

    k_wconv<<<1024, 256, 0, stream>>>(Wq, Wk, Wv, Wo, Wcat, Wob);
    int nch = 1024 / CN;
    for (int ch = 0; ch < nch; ++ch) {
        int n0 = ch * CN;
        int nrow = (CN * 128) / 256;    // 256-row tiles in this chunk (divisible by 8 for CN>=16)
        k_xconv<<<CN*32, 256, 0, stream>>>(x, xb, n0);
        k_gemm4<6, false><<<nrow*6, 512, 131072, stream>>>(xb, Wcat, QKV2, nullptr, 0, nrow, planesz);
        k_attn<<<dim3(8, CN), 256, 0, stream>>>(QKV2, QKV2 + planesz, QKV2 + 2*(size_t)planesz, xb);
        k_gemm4<2, true ><<<nrow*2, 512, 131072, stream>>>(xb, Wob, d_out, bo, n0, nrow, 0);
    }
}

// Round 8
// 615.374 us; speedup vs baseline: 1.0452x; 1.0273x over previous
//
#include <hip/hip_runtime.h>
#include <stdint.h>

// Axial attention (H axis), N=8 H=128 W=128 C=512, GROUPS=8, gp=64.
// Pipeline: wconv -> xconv(bf16+permute) -> QKV GEMM -> attn -> outproj.
// GEMM (k_gemm4): 256x256 block, 8 waves (2x4, wave-out 128x64), BK=32 K-steps,
// 4 rotating 32KB buffers (128 KiB LDS), depth-3 prefetch, counted vmcnt(8),
// slot-XOR swizzle (R6-verified conflicts=0).
// OUTPROJ tile remap (R8): M-rows = (fixed nb, h-pair) x w[0..128) so the NHWC f32
// output writes are DENSE (2KB row stride within a 512KB window) instead of 256KB-stride
// scatter; O-reads become 64B-grain strided (reads tolerate, writes don't).
// ws: Q/K/V as separate [M][512] planes; O overwrites xb ([M][512]).

typedef __attribute__((ext_vector_type(4))) float f32x4;
typedef __attribute__((ext_vector_type(8))) short bf16x8;
typedef unsigned short u16;
typedef unsigned int u32;

#define CBAR() asm volatile("" ::: "memory")
#define SBAR() do { CBAR(); __builtin_amdgcn_s_barrier(); CBAR(); } while(0)
#define LGKM0() do { asm volatile("s_waitcnt lgkmcnt(0)" ::: "memory"); __builtin_amdgcn_sched_barrier(0); } while(0)
#define VMC(n) asm volatile("s_waitcnt vmcnt(" #n ")" ::: "memory")

static __device__ __forceinline__ u16 f2bf(float f){
    union { float f; u32 u; } v; v.f = f;
    u32 r = v.u + 0x7fffu + ((v.u >> 16) & 1u);   // RNE
    return (u16)(r >> 16);
}

static __device__ __forceinline__ void gload16(const void* g, void* l){
    __builtin_amdgcn_global_load_lds((const __attribute__((address_space(1))) void*)g,
                                     (__attribute__((address_space(3))) void*)l, 16, 0, 0);
}

// ---------------- weights fp32 -> bf16 ----------------
__global__ void k_wconv(const float* __restrict__ Wq, const float* __restrict__ Wk,
                        const float* __restrict__ Wv, const float* __restrict__ Wo,
                        u16* __restrict__ Wcat, u16* __restrict__ Wob){
    int e = (blockIdx.x * 256 + threadIdx.x) * 4;
    if (e < 1536*512) {
        int row = e >> 9, col = e & 511;
        const float* s = (row < 512) ? (Wq + row*512)
                        : (row < 1024 ? Wk + (row-512)*512 : Wv + (row-1024)*512);
        float4 v = *(const float4*)(s + col);
        ushort4 o = { f2bf(v.x), f2bf(v.y), f2bf(v.z), f2bf(v.w) };
        *(ushort4*)(Wcat + e) = o;
    } else {
        int e2 = e - 1536*512;
        float4 v = *(const float4*)(Wo + e2);
        ushort4 o = { f2bf(v.x), f2bf(v.y), f2bf(v.z), f2bf(v.w) };
        *(ushort4*)(Wob + e2) = o;
    }
}

// ---------------- x fp32 (N,H,W,C) -> xb bf16 [(n0+nl)*128+h][512] ----------------
__global__ void k_xconv(const float* __restrict__ x, u16* __restrict__ xb, int n0){
    int t = blockIdx.x * 256 + threadIdx.x;
    int ml = t >> 6;                 // chunk-local token row
    int c0 = (t & 63) << 3;          // 8 channels per thread
    int nl = ml >> 7, h = ml & 127;
    int n = n0 + nl, nb = n >> 7, w = n & 127;
    const float* src = x + (size_t)((nb*128 + h)*128 + w) * 512 + c0;
    float4 a = *(const float4*)(src);
    float4 b = *(const float4*)(src + 4);
    uint4 o;
    o.x = (u32)f2bf(a.x) | ((u32)f2bf(a.y) << 16);
    o.y = (u32)f2bf(a.z) | ((u32)f2bf(a.w) << 16);
    o.z = (u32)f2bf(b.x) | ((u32)f2bf(b.y) << 16);
    o.w = (u32)f2bf(b.z) | ((u32)f2bf(b.w) << 16);
    *(uint4*)(xb + (size_t)ml*512 + c0) = o;
}

// ---------------- 256x256 GEMM, 4-buffer depth-3 pipeline: C = A[Mx512] * B^T ----------------
// Buf b (32KB) = A slab [256 rows][64B] + B slab [256 rows][64B] (one BK=32 K-window).
// Swizzle (R6-verified, 0 conflicts): LDS 16B-slot q of row r holds global chunk q^((r>>1)&3);
// frag read at slot lg^((r>>1)&3).  Per-lane stage bases hoisted out of the K-loop.
// Step t (2 phases): p0 {frags A0-3+B0-3; stageA(t+3); bar; lgkm0; 16 MFMA; bar}
//                    p1 {frags A4-7;      stageB(t+3); bar; lgkm0; 16 MFMA; vmcnt(8); bar}
// OUTPROJ: tile-row rho -> (w = rho&127, hh = rho>>7); A row = (nbL*128+w)*128 + h0+hh;
//          out row = (nbG*128 + h0+hh)*128 + w  (dense 2KB-stride writes).
template<int NCOL, bool OUTPROJ>
__global__ __launch_bounds__(512, 2) void k_gemm4(const u16* __restrict__ A, const u16* __restrict__ B,
                                                  void* __restrict__ Cout, const float* __restrict__ bias,
                                                  int n0, int nrow, int planesz){
    extern __shared__ char smc[];
    const int tid = threadIdx.x;
    const int wid = tid >> 6, lane = tid & 63, lg = lane >> 4, li = lane & 15;
    const int wm = wid >> 2, wn = wid & 3;           // 2 x 4 wave grid, wave out 128x64
    const int bid = blockIdx.x;
    const int xcd = bid & 7, l = bid >> 3;
    const int row_tile = xcd * (nrow >> 3) + l / NCOL;
    const int col_tile = l % NCOL;
    const int m0 = row_tile * 256, nn0 = col_tile * 256;
    const int nbL = row_tile >> 6, h0 = (row_tile & 63) * 2;   // OUTPROJ geometry

    // per-lane stage source bases (incl. slot-XOR pre-swizzle), hoisted out of the K-loop
    const char* baseA[2]; const char* baseB[2]; int dstR[2];
    #pragma unroll
    for (int i = 0; i < 2; ++i) {
        int R = wid*32 + i*16;
        int r = R + (lane >> 2);
        int cq = (lane & 3) ^ ((r >> 1) & 3);
        long arow;
        if (OUTPROJ) arow = ((long)nbL*128 + (r & 127))*128 + h0 + (r >> 7);
        else         arow = m0 + r;
        baseA[i] = (const char*)(A + (size_t)arow*512) + cq*16;
        baseB[i] = (const char*)(B + (size_t)(nn0 + r)*512) + cq*16;
        dstR[i] = R;
    }
    auto stageA = [&](int st){
        char* sl = smc + (st & 3)*32768;
        #pragma unroll
        for (int i = 0; i < 2; ++i)
            gload16(baseA[i] + st*64, sl + dstR[i]*64);
    };
    auto stageB = [&](int st){
        char* sl = smc + (st & 3)*32768 + 16384;
        #pragma unroll
        for (int i = 0; i < 2; ++i)
            gload16(baseB[i] + st*64, sl + dstR[i]*64);
    };

    f32x4 acc[8][4];
    #pragma unroll
    for (int i = 0; i < 8; ++i)
        #pragma unroll
        for (int j = 0; j < 4; ++j)
            acc[i][j] = f32x4{0.f, 0.f, 0.f, 0.f};

    // prologue: stage steps 0,1,2 (12 loads/wave); wait step 0 landed (8 = steps 1,2 in flight)
    stageA(0); stageB(0);
    stageA(1); stageB(1);
    stageA(2); stageB(2);
    VMC(8);
    SBAR();

    bf16x8 af[4], bfr[4];
    for (int t = 0; t < 16; ++t) {
        char* sl = smc + (t & 3)*32768;

        // ---- p0: frags A[0..3] + B[0..3], MFMA upper half
        #pragma unroll
        for (int f = 0; f < 4; ++f) {
            int ra = wm*128 + f*16 + li;
            af[f] = *(const bf16x8*)(sl + ra*64 + (((lg ^ (ra >> 1)) & 3) << 4));
        }
        #pragma unroll
        for (int f = 0; f < 4; ++f) {
            int rb = wn*64 + f*16 + li;
            bfr[f] = *(const bf16x8*)(sl + 16384 + rb*64 + (((lg ^ (rb >> 1)) & 3) << 4));
        }
        if (t < 13) stageA(t + 3);
        SBAR(); LGKM0();
        __builtin_amdgcn_s_setprio(1);
        #pragma unroll
        for (int fi = 0; fi < 4; ++fi)
            #pragma unroll
            for (int fj = 0; fj < 4; ++fj)
                acc[fi][fj] = __builtin_amdgcn_mfma_f32_16x16x32_bf16(af[fi], bfr[fj], acc[fi][fj], 0, 0, 0);
        __builtin_amdgcn_s_setprio(0);
        SBAR();

        // ---- p1: frags A[4..7] (B in regs), MFMA lower half
        #pragma unroll
        for (int f = 0; f < 4; ++f) {
            int ra = wm*128 + (4 + f)*16 + li;
            af[f] = *(const bf16x8*)(sl + ra*64 + (((lg ^ (ra >> 1)) & 3) << 4));
        }
        if (t < 13) stageB(t + 3);
        SBAR(); LGKM0();
        __builtin_amdgcn_s_setprio(1);
        #pragma unroll
        for (int fi = 0; fi < 4; ++fi)
            #pragma unroll
            for (int fj = 0; fj < 4; ++fj)
                acc[4 + fi][fj] = __builtin_amdgcn_mfma_f32_16x16x32_bf16(af[fi], bfr[fj], acc[4 + fi][fj], 0, 0, 0);
        __builtin_amdgcn_s_setprio(0);
        if (t < 13)      { VMC(8); }   // retire step t+1's 4 loads; 8 in flight (t+2,t+3)
        else if (t == 13){ VMC(4); }   // retire step 14
        else if (t == 14){ VMC(0); }   // retire step 15
        SBAR();
    }

    // epilogue
    if (!OUTPROJ) {
        // C = Q/K/V planes, each [chunkrows][512]; plane from output col range
        u16* Cp = (u16*)Cout + (size_t)(nn0 >> 9) * planesz;
        const int cb = (nn0 & 511) + wn*64;
        #pragma unroll
        for (int mf = 0; mf < 8; ++mf)
            #pragma unroll
            for (int nf = 0; nf < 4; ++nf)
                #pragma unroll
                for (int r = 0; r < 4; ++r) {
                    int row = m0 + wm*128 + mf*16 + lg*4 + r;
                    int col = cb + nf*16 + li;
                    Cp[(size_t)row*512 + col] = f2bf(acc[mf][nf][r]);
                }
    } else {
        float* C = (float*)Cout;
        const int nbG = (n0 >> 7) + nbL;
        #pragma unroll
        for (int mf = 0; mf < 8; ++mf)
            #pragma unroll
            for (int nf = 0; nf < 4; ++nf)
                #pragma unroll
                for (int r = 0; r < 4; ++r) {
                    int rho = wm*128 + mf*16 + lg*4 + r;       // tile-local row
                    int w = rho & 127, hh = rho >> 7;
                    int col = nn0 + wn*64 + nf*16 + li;
                    size_t orow = (size_t)(nbG*128 + h0 + hh)*128 + w;
                    C[orow*512 + col] = acc[mf][nf][r] + bias[col];
                }
    }
}

// ---------------- attention: one block per (n_local, group), 4 waves x 32 rows ----------------
__global__ __launch_bounds__(256, 2) void k_attn(const u16* __restrict__ Qpl, const u16* __restrict__ Kpl,
                                                 const u16* __restrict__ Vpl, u16* __restrict__ Ob){
    // LDS: [0,16K) Qs swz, [16K,32K) Ks swz; P overlays [0,34816) after S-phase;
    //      Vt [34816, 34816+17408): [c=64][stride 272B] bf16
    __shared__ char sm[52224];
    const int g = blockIdx.x;
    const int nl = blockIdx.y;
    const int tid = threadIdx.x;
    const int wid = tid >> 6, lane = tid & 63, lg = lane >> 4, li = lane & 15;

    const u16* Qg = Qpl + (size_t)nl*128*512 + g*64;
    const u16* Kg = Kpl + (size_t)nl*128*512 + g*64;
    const u16* Vg = Vpl + (size_t)nl*128*512 + g*64;
    u16*       Og = Ob  + (size_t)nl*128*512 + g*64;

    #pragma unroll
    for (int it = 0; it < 4; ++it) {
        int gi = it*256 + tid;
        int row = gi >> 3, gs = gi & 7;
        int sw = (gs ^ (row & 7)) << 4;
        gload16((const char*)(Qg + (size_t)row*512) + sw, sm + it*4096 + wid*1024);
        gload16((const char*)(Kg + (size_t)row*512) + sw, sm + 16384 + it*4096 + wid*1024);
    }
    {   // V transposed: Vt[c][j] — vectorized global loads, scalar LDS scatter
        int j = tid & 127, ch = tid >> 7;
        const u16* src = Vg + (size_t)j*512 + ch*32;
        uint4 a0 = *(const uint4*)(src);
        uint4 a1 = *(const uint4*)(src + 8);
        uint4 a2 = *(const uint4*)(src + 16);
        uint4 a3 = *(const uint4*)(src + 24);
        u32 w[16] = {a0.x,a0.y,a0.z,a0.w, a1.x,a1.y,a1.z,a1.w,
                     a2.x,a2.y,a2.z,a2.w, a3.x,a3.y,a3.z,a3.w};
        char* dst = sm + 34816 + ch*32*272 + j*2;
        #pragma unroll
        for (int cc = 0; cc < 32; ++cc) {
            u32 word = w[cc >> 1];
            u16 val = (cc & 1) ? (u16)(word >> 16) : (u16)(word & 0xffffu);
            *(u16*)(dst + cc*272) = val;
        }
    }
    __syncthreads();

    const int i0w = wid*32;
    f32x4 s[2][8];
    #pragma unroll
    for (int t = 0; t < 2; ++t)
        #pragma unroll
        for (int tj = 0; tj < 8; ++tj)
            s[t][tj] = f32x4{0.f,0.f,0.f,0.f};

    #pragma unroll
    for (int ks = 0; ks < 2; ++ks) {
        bf16x8 qf[2];
        #pragma unroll
        for (int t = 0; t < 2; ++t) {
            int ra = i0w + t*16 + li;
            qf[t] = *(const bf16x8*)(sm + ra*128 + ((ks*64 + lg*16) ^ ((ra & 7) << 4)));
        }
        #pragma unroll
        for (int tj = 0; tj < 8; ++tj) {
            int rb = tj*16 + li;
            bf16x8 kf = *(const bf16x8*)(sm + 16384 + rb*128 + ((ks*64 + lg*16) ^ ((rb & 7) << 4)));
            #pragma unroll
            for (int t = 0; t < 2; ++t)
                s[t][tj] = __builtin_amdgcn_mfma_f32_16x16x32_bf16(qf[t], kf, s[t][tj], 0, 0, 0);
        }
    }
    __syncthreads();   // Q/K LDS dead -> P overlay is now safe

    // wave-parallel softmax over j (scale 1/8 folded into exp arg)
    char* pb = sm + wid*8704;     // per-wave P [32 rows][272B stride]
    #pragma unroll
    for (int t = 0; t < 2; ++t) {
        #pragma unroll
        for (int r = 0; r < 4; ++r) {
            float mx = -1e30f;
            #pragma unroll
            for (int tj = 0; tj < 8; ++tj) mx = fmaxf(mx, s[t][tj][r]);
            #pragma unroll
            for (int off = 1; off < 16; off <<= 1) mx = fmaxf(mx, __shfl_xor(mx, off, 64));
            float p[8]; float sum = 0.f;
            #pragma unroll
            for (int tj = 0; tj < 8; ++tj) { p[tj] = __expf((s[t][tj][r] - mx)*0.125f); sum += p[tj]; }
            #pragma unroll
            for (int off = 1; off < 16; off <<= 1) sum += __shfl_xor(sum, off, 64);
            float inv = 1.0f / sum;
            int prow = t*16 + lg*4 + r;
            #pragma unroll
            for (int tj = 0; tj < 8; ++tj)
                *(u16*)(pb + prow*272 + (tj*16 + li)*2) = f2bf(p[tj]*inv);
        }
    }

    // O = P @ V
    f32x4 o[2][4];
    #pragma unroll
    for (int t = 0; t < 2; ++t)
        #pragma unroll
        for (int tc = 0; tc < 4; ++tc)
            o[t][tc] = f32x4{0.f,0.f,0.f,0.f};

    #pragma unroll
    for (int ks = 0; ks < 4; ++ks) {
        bf16x8 pf[2];
        #pragma unroll
        for (int t = 0; t < 2; ++t)
            pf[t] = *(const bf16x8*)(pb + (t*16 + li)*272 + (ks*64 + lg*16));
        #pragma unroll
        for (int tc = 0; tc < 4; ++tc) {
            bf16x8 vf = *(const bf16x8*)(sm + 34816 + (tc*16 + li)*272 + (ks*64 + lg*16));
            #pragma unroll
            for (int t = 0; t < 2; ++t)
                o[t][tc] = __builtin_amdgcn_mfma_f32_16x16x32_bf16(pf[t], vf, o[t][tc], 0, 0, 0);
        }
    }

    #pragma unroll
    for (int t = 0; t < 2; ++t)
        #pragma unroll
        for (int tc = 0; tc < 4; ++tc)
            #pragma unroll
            for (int r = 0; r < 4; ++r) {
                int irow = i0w + t*16 + lg*4 + r;
                int col = tc*16 + li;
                Og[(size_t)irow*512 + col] = f2bf(o[t][tc][r]);
            }
}

extern "C" void kernel_launch(void* const* d_in, const int* in_sizes, int n_in,
                              void* d_out, int out_size, void* d_ws, size_t ws_size,
                              hipStream_t stream){
    const float* x  = (const float*)d_in[0];
    const float* Wq = (const float*)d_in[1];
    const float* Wk = (const float*)d_in[2];
    const float* Wv = (const float*)d_in[3];
    const float* Wo = (const float*)d_in[4];
    const float* bo = (const float*)d_in[5];

    char* ws = (char*)d_ws;
    u16* Wcat = (u16*)ws;               // 1536*512 bf16
    u16* Wob  = Wcat + 1536*512;        // 512*512 bf16 ; weights end at 2097152 B

    // chunk over the 1024 attention rows: per chunk = CN*128*512*2 (xb) + 3x same (QKV planes)
    // CN floored at 128 so each chunk spans whole nb slices (OUTPROJ remap needs it)
    int CN = 1024;
    while (CN > 128 && (size_t)2097152 + (size_t)CN*524288 > ws_size) CN >>= 1;
    u16* xb   = (u16*)(ws + 2097152);      // also reused as O buffer by attn/outproj
    u16* QKV2 = xb + (size_t)CN*128*512;   // 3 planes [CN*128][512]
    int planesz = CN*128*512;

    // 128 KiB dynamic LDS for the 4-buffer GEMMs (idempotent; not a stream op, capture-safe)
    hipFuncSetAttribute((const void*)&k_gemm4<6, false>,
                        hipFuncAttributeMaxDynamicSharedMemorySize, 131072);
    hipFuncSetAttribute((const void*)&k_gemm4<2, true>,
                        hipFuncAttributeMaxDynamicSharedMemorySize, 131072);

    k_wconv<<<1024, 256, 0, stream>>>(Wq, Wk, Wv, Wo, Wcat, Wob);
    int nch = 1024 / CN;
    for (int ch = 0; ch < nch; ++ch) {
        int n0 = ch * CN;
        int nrow = (CN * 128) / 256;    // 256-row tiles in this chunk (multiple of 64)
        k_xconv<<<CN*32, 256, 0, stream>>>(x, xb, n0);
        k_gemm4<6, false><<<nrow*6, 512, 131072, stream>>>(xb, Wcat, QKV2, nullptr, 0, nrow, planesz);
        k_attn<<<dim3(8, CN), 256, 0, stream>>>(QKV2, QKV2 + planesz, QKV2 + 2*(size_t)planesz, xb);
        k_gemm4<2, true ><<<nrow*2, 512, 131072, stream>>>(xb, Wob, d_out, bo, n0, nrow, 0);
    }
}